// Round 6
// baseline (16802.464 us; speedup 1.0000x reference)
//
#include <hip/hip_runtime.h>
#include <hip/hip_cooperative_groups.h>
#include <math.h>

namespace cg = cooperative_groups;

#define Bq 512
#define Tq 128
#define Fq 64
#define Uq 1024
#define OSTEPS 24

typedef __bf16 bf16x8 __attribute__((ext_vector_type(8)));
typedef __bf16 bf16x2 __attribute__((ext_vector_type(2)));
typedef float f32x16 __attribute__((ext_vector_type(16)));
typedef float f32x4 __attribute__((ext_vector_type(4)));
typedef float f32x2 __attribute__((ext_vector_type(2)));

__device__ __forceinline__ float sigmoidf_(float x) {
    return 1.0f / (1.0f + __expf(-x));
}
__device__ __forceinline__ float tanhf_(float x) {
    return 2.0f / (1.0f + __expf(-2.0f * x)) - 1.0f;
}

// barrier WITHOUT vmcnt drain: LDS-complete + hw barrier
#define BAR() do {                                             \
    asm volatile("s_waitcnt lgkmcnt(0)" ::: "memory");         \
    __builtin_amdgcn_s_barrier();                              \
} while (0)

#define MFMA(a, b, c) __builtin_amdgcn_mfma_f32_32x32x16_bf16(a, b, c, 0, 0, 0)

#define GLL(gp, lp) __builtin_amdgcn_global_load_lds(                         \
    (const __attribute__((address_space(1))) void*)(gp),                      \
    (__attribute__((address_space(3))) void*)(lp), 16, 0, 0)

// ---------------------------------------------------------------------------
// Pack Wh [1024][4096] + Wx [64][4096] into per-block B fragments, hi/lo bf16.
// Bp[slot*128 + pl*64 + lane], slot = ((bn*2+nh)*4+kq)*17 + j
//   kc16 = 4j+kq; k = kc16*16 + (lane>>5)*8 + e
//   u = bn*16 + nh*8 + ((lane&31)>>2); g = (lane&31)&3; zcol = g*1024 + u
// ---------------------------------------------------------------------------
__global__ __launch_bounds__(256)
void pack_w(const float* __restrict__ Wh, const float* __restrict__ Wx,
            bf16x8* __restrict__ Bp)
{
    const int id = blockIdx.x * 256 + threadIdx.x;   // 557056 total
    const int lane = id & 63;
    const int rest = id >> 6;
    const int j  = rest % 17;
    const int r2 = rest / 17;
    const int kq = r2 & 3;
    const int r3 = r2 >> 2;
    const int nh = r3 & 1;
    const int bn = r3 >> 1;
    const int kc16 = 4 * j + kq;
    const int k0 = kc16 * 16 + (lane >> 5) * 8;
    const int u  = bn * 16 + nh * 8 + ((lane & 31) >> 2);
    const int g  = (lane & 31) & 3;
    const int zc = g * Uq + u;
    bf16x8 hv, lv;
#pragma unroll
    for (int e = 0; e < 8; ++e) {
        const int k = k0 + e;
        const float v = (k < Uq) ? Wh[(size_t)k * (4 * Uq) + zc]
                                 : Wx[(size_t)(k - Uq) * (4 * Uq) + zc];
        const __bf16 h_ = (__bf16)v;
        hv[e] = h_;
        lv[e] = (__bf16)(v - (float)h_);
    }
    Bp[(size_t)rest * 128 + lane]      = hv;
    Bp[(size_t)rest * 128 + 64 + lane] = lv;
}

// ---------------------------------------------------------------------------
// Persistent fused LSTM: all 151 steps + 24 readouts in one cooperative launch.
// Grid 256 blocks x 512 threads (1 block/CU). Block = 128 rows x 16 units.
//   bm = bid&3 (row tile of 128), bn = bid>>2 (unit tile of 16).
// Waves: nh = w&1 (32-col half), kq = w>>1 (kc16 = 4j+kq).
// B (its 64 z-cols, full K, hi+lo) lives in 136 VGPR/thread for the whole run.
// c lives in 4 VGPR/thread. h stored as MFMA-A fragments (hi/lo planes),
// staged chunk-by-chunk with global_load_lds (linear, zero staging VGPRs).
// ---------------------------------------------------------------------------
__global__ __launch_bounds__(512, 2)
void lstm_persist(const bf16x8* __restrict__ Bp,
                  const float* __restrict__ inputs,   // [512][128][64]
                  const float* __restrict__ bias,     // [4096]
                  const float* __restrict__ Wd,       // [1024][64]
                  const float* __restrict__ bd,       // [64]
                  __bf16* __restrict__ ap0,           // h frag plane, parity 0
                  __bf16* __restrict__ ap1,           // h frag plane, parity 1
                  float* __restrict__ pbuf,           // [512][64] feedback
                  float* __restrict__ out)            // [512][24][64]
{
    // As[buf 4][kc 4][pl 2][mt 4][lane 64] bf16x8 : 4 x 32768 B = 128 KB
    // zsd f32[4][64][68] (69632 B) unions bufs 0..2 ; red f32[2][4][64] unions too
    __shared__ __align__(16) char smem[131072];

    cg::grid_group grid = cg::this_grid();

    const int tid = threadIdx.x;
    const int l   = tid & 63;
    const int w   = tid >> 6;
    const int nh  = w & 1;
    const int kq  = w >> 1;
    const int bid = (int)blockIdx.x;
    const int bm  = bid & 3;
    const int bn  = bid >> 2;
    const int row0 = bm * 128;

    // staging roles: wave stages (s_kc, s_pl) x 4 mt per chunk
    const int s_kc = w >> 1;
    const int s_pl = w & 1;
    // x-stage decomposition: 128 rows x 4 threads (2 octets each)
    const int xrow = tid >> 2;
    const int xo   = (tid & 3) * 2;
    // epilogue decomposition: 64 rows x 8 unit-pairs
    const int erow = tid >> 3;
    const int eup  = tid & 7;
    // readout decomposition
    const int rf = tid & 63;
    const int rk = (tid >> 6) & 3;
    const int rr = tid >> 8;

    // ---- load B into registers (persistent) ----
    bf16x8 Bh[17], Bl[17];
    {
        const bf16x8* bb = Bp + (size_t)(((bn * 2 + nh) * 4 + kq) * 17) * 128 + l;
#pragma unroll
        for (int j = 0; j < 17; ++j) {
            Bh[j] = bb[j * 128];
            Bl[j] = bb[j * 128 + 64];
        }
    }

    float cc[4] = {0.0f, 0.0f, 0.0f, 0.0f};   // c cells: [pass mh][unit parity]

#define STAGE(J, BUF) do {                                                       \
    const int kcg_ = 4 * (J) + s_kc;                                             \
    const __bf16* g_ = apr + ((size_t)(((bm * 4) * 64 + kcg_) * 2 + s_pl) * 64 + l) * 8; \
    char* lb_ = smem + (BUF) * 32768 + ((s_kc * 2 + s_pl) * 4) * 1024;           \
    _Pragma("unroll")                                                            \
    for (int mt_ = 0; mt_ < 4; ++mt_)                                            \
        GLL(g_ + (size_t)mt_ * 65536, lb_ + mt_ * 1024);                         \
} while (0)

#define COMPUTE(J, BUF) do {                                                     \
    const char* b0_ = smem + (BUF) * 32768 + ((kq * 2 + 0) * 4) * 1024;          \
    const char* b1_ = smem + (BUF) * 32768 + ((kq * 2 + 1) * 4) * 1024;          \
    _Pragma("unroll")                                                            \
    for (int m_ = 0; m_ < 4; ++m_) {                                             \
        bf16x8 ah_ = *(const bf16x8*)(b0_ + m_ * 1024 + l * 16);                 \
        bf16x8 al_ = *(const bf16x8*)(b1_ + m_ * 1024 + l * 16);                 \
        acc[m_] = MFMA(ah_, Bh[J], acc[m_]);                                     \
        acc[m_] = MFMA(al_, Bh[J], acc[m_]);                                     \
        acc[m_] = MFMA(ah_, Bl[J], acc[m_]);                                     \
    }                                                                            \
} while (0)

    for (int t = 0; t < 151; ++t) {
        const __bf16* apr = (t & 1) ? ap1 : ap0;
        __bf16* apw = (t & 1) ? ap0 : ap1;
        const float* xs;
        size_t xstr;
        if (t < Tq) { xs = inputs + (size_t)t * 64; xstr = (size_t)Tq * Fq; }
        else        { xs = pbuf;                    xstr = Fq; }

        // ---- x-stage into dedicated buf3 (f32 -> hi/lo bf16 frags) ----
        {
            const float* xp = xs + (size_t)(row0 + xrow) * xstr + xo * 8;
            f32x4 v0 = *(const f32x4*)xp;
            f32x4 v1 = *(const f32x4*)(xp + 4);
            f32x4 v2 = *(const f32x4*)(xp + 8);
            f32x4 v3 = *(const f32x4*)(xp + 12);
            bf16x8 h0, l0, h1, l1;
#pragma unroll
            for (int e = 0; e < 4; ++e) {
                __bf16 a = (__bf16)v0[e]; h0[e] = a; l0[e] = (__bf16)(v0[e] - (float)a);
                __bf16 b2 = (__bf16)v1[e]; h0[4+e] = b2; l0[4+e] = (__bf16)(v1[e] - (float)b2);
                __bf16 c2 = (__bf16)v2[e]; h1[e] = c2; l1[e] = (__bf16)(v2[e] - (float)c2);
                __bf16 d2 = (__bf16)v3[e]; h1[4+e] = d2; l1[4+e] = (__bf16)(v3[e] - (float)d2);
            }
            const int q   = xo >> 1;
            const int mtx = xrow >> 5;
            const int lnx = xrow & 31;
            char* bhp = smem + 3 * 32768 + ((q * 2 + 0) * 4 + mtx) * 1024;
            char* blp = smem + 3 * 32768 + ((q * 2 + 1) * 4 + mtx) * 1024;
            *(bf16x8*)(bhp + lnx * 16)        = h0;
            *(bf16x8*)(bhp + (lnx + 32) * 16) = h1;
            *(bf16x8*)(blp + lnx * 16)        = l0;
            *(bf16x8*)(blp + (lnx + 32) * 16) = l1;
        }

        f32x16 acc[4];
#pragma unroll
        for (int m = 0; m < 4; ++m)
#pragma unroll
            for (int i = 0; i < 16; ++i) acc[m][i] = 0.0f;

        if (t > 0) {
            STAGE(0, 0);
#pragma unroll
            for (int j = 0; j < 16; ++j) {
                if (j < 15) {
                    STAGE(j + 1, (j + 1) % 3);
                    asm volatile("s_waitcnt vmcnt(4)" ::: "memory");
                } else {
                    asm volatile("s_waitcnt vmcnt(0)" ::: "memory");
                }
                BAR();
                COMPUTE(j, j % 3);
            }
        }
        BAR();              // x-stage ds_writes drained (and buf0..2 reads done)
        COMPUTE(16, 3);

        // ---- epilogue: zsd exchange (2 passes over row halves) ----
        BAR();
        float* zsd = (float*)smem;   // [4][64][68]
#pragma unroll
        for (int mh = 0; mh < 2; ++mh) {
#pragma unroll
            for (int mm = 0; mm < 2; ++mm) {
                const int m = mh * 2 + mm;
#pragma unroll
                for (int r = 0; r < 16; ++r) {
                    const int rowi = mm * 32 + (r & 3) + 8 * (r >> 2) + 4 * (l >> 5);
                    zsd[(kq * 64 + rowi) * 68 + nh * 32 + (l & 31)] = acc[m][r];
                }
            }
            BAR();
            {
                const int colb = (eup >> 2) * 32 + (eup & 3) * 8;
                f32x4 ze = {0, 0, 0, 0}, zo = {0, 0, 0, 0};
#pragma unroll
                for (int q2 = 0; q2 < 4; ++q2) {
                    const float* zp = &zsd[(q2 * 64 + erow) * 68 + colb];
                    ze += *(const f32x4*)zp;
                    zo += *(const f32x4*)(zp + 4);
                }
                const int ug = bn * 16 + eup * 2;
                f32x2 bi  = *(const f32x2*)(bias + 0 * Uq + ug);
                f32x2 bf2 = *(const f32x2*)(bias + 1 * Uq + ug);
                f32x2 bg2 = *(const f32x2*)(bias + 2 * Uq + ug);
                f32x2 bo2 = *(const f32x2*)(bias + 3 * Uq + ug);
                float vi = sigmoidf_(ze[0] + bi[0]);
                float vf = sigmoidf_(ze[1] + bf2[0]);
                float vg = tanhf_  (ze[2] + bg2[0]);
                float vo = sigmoidf_(ze[3] + bo2[0]);
                float cn0 = vf * cc[mh * 2 + 0] + vi * vg;
                cc[mh * 2 + 0] = cn0;
                float h0v = vo * tanhf_(cn0);
                vi = sigmoidf_(zo[0] + bi[1]);
                vf = sigmoidf_(zo[1] + bf2[1]);
                vg = tanhf_  (zo[2] + bg2[1]);
                vo = sigmoidf_(zo[3] + bo2[1]);
                float cn1 = vf * cc[mh * 2 + 1] + vi * vg;
                cc[mh * 2 + 1] = cn1;
                float h1v = vo * tanhf_(cn1);

                const int grow = row0 + mh * 64 + erow;
                const int mtg  = grow >> 5;
                const int lane_h = (grow & 31) + 32 * (eup >> 2);
                const int eo = (2 * eup) & 7;
                bf16x2 hh2, hl2;
                __bf16 a = (__bf16)h0v; hh2[0] = a;
                hl2[0] = (__bf16)(h0v - (float)a);
                a = (__bf16)h1v; hh2[1] = a;
                hl2[1] = (__bf16)(h1v - (float)a);
                *(bf16x2*)((char*)apw + ((size_t)((mtg * 64 + bn) * 2 + 0) * 64 + lane_h) * 16 + eo * 2) = hh2;
                *(bf16x2*)((char*)apw + ((size_t)((mtg * 64 + bn) * 2 + 1) * 64 + lane_h) * 16 + eo * 2) = hl2;
            }
            if (mh == 0) BAR();
        }

        __threadfence();
        grid.sync();

        // ---- fused readout on decode steps: p = h@Wd + bd ----
        if (t >= Tq - 1) {
            const int s = t - (Tq - 1);
            const int row = bid * 2 + rr;
            const int mt2 = row >> 5, l31 = row & 31;
            float part = 0.0f;
#pragma unroll 4
            for (int kc = rk * 16; kc < rk * 16 + 16; ++kc) {
#pragma unroll
                for (int hl = 0; hl < 2; ++hl) {
                    const bf16x8 h8  = *(const bf16x8*)(apw + ((size_t)((mt2 * 64 + kc) * 2 + 0) * 64 + l31 + 32 * hl) * 8);
                    const bf16x8 lo8 = *(const bf16x8*)(apw + ((size_t)((mt2 * 64 + kc) * 2 + 1) * 64 + l31 + 32 * hl) * 8);
                    const int k0 = kc * 16 + hl * 8;
                    const float* wp = Wd + (size_t)k0 * 64 + rf;
#pragma unroll
                    for (int e = 0; e < 8; ++e)
                        part = fmaf((float)h8[e] + (float)lo8[e], wp[e * 64], part);
                }
            }
            float* red = (float*)smem;   // [2][4][64]
            red[(rr * 4 + rk) * 64 + rf] = part;
            BAR();
            if (tid < 128) {
                const int rr2 = tid >> 6, f2 = tid & 63;
                float sum = red[(rr2 * 4 + 0) * 64 + f2] + red[(rr2 * 4 + 1) * 64 + f2]
                          + red[(rr2 * 4 + 2) * 64 + f2] + red[(rr2 * 4 + 3) * 64 + f2] + bd[f2];
                const int row2 = bid * 2 + rr2;
                out[((size_t)row2 * OSTEPS + s) * 64 + f2] = sum;
                pbuf[(size_t)row2 * 64 + f2] = sum;
            }
            if (t < 150) { __threadfence(); grid.sync(); }
        }
    }
#undef STAGE
#undef COMPUTE
}

extern "C" void kernel_launch(void* const* d_in, const int* in_sizes, int n_in,
                              void* d_out, int out_size, void* d_ws, size_t ws_size,
                              hipStream_t stream) {
    const float* inputs = (const float*)d_in[0];  // [512][128][64]
    const float* Wx     = (const float*)d_in[1];  // [64][4096]
    const float* Wh     = (const float*)d_in[2];  // [1024][4096]
    const float* b      = (const float*)d_in[3];  // [4096]
    const float* Wd     = (const float*)d_in[4];  // [1024][64]
    const float* bd     = (const float*)d_in[5];  // [64]
    float* out = (float*)d_out;

    // workspace: Bp (17,825,792 B) | ap0 (2,097,152) | ap1 (2,097,152) | pbuf (131,072)
    char* ws = (char*)d_ws;
    bf16x8* Bp = (bf16x8*)ws;
    __bf16* ap0 = (__bf16*)(ws + 17825792);
    __bf16* ap1 = (__bf16*)(ws + 17825792 + 2097152);
    float* pbuf = (float*)(ws + 17825792 + 2 * 2097152);

    pack_w<<<2176, 256, 0, stream>>>(Wh, Wx, Bp);

    void* args[] = {(void*)&Bp, (void*)&inputs, (void*)&b, (void*)&Wd, (void*)&bd,
                    (void*)&ap0, (void*)&ap1, (void*)&pbuf, (void*)&out};
    hipLaunchCooperativeKernel((const void*)lstm_persist, dim3(256), dim3(512),
                               args, 0, stream);
}

// Round 7
// 3385.286 us; speedup vs baseline: 4.9634x; 4.9634x over previous
//
#include <hip/hip_runtime.h>
#include <math.h>

#define Bq 512
#define Tq 128
#define Fq 64
#define Uq 1024
#define OSTEPS 24
#define NKC16 68

typedef __bf16 bf16x8 __attribute__((ext_vector_type(8)));
typedef __bf16 bf16x2 __attribute__((ext_vector_type(2)));
typedef float f32x16 __attribute__((ext_vector_type(16)));
typedef float f32x4 __attribute__((ext_vector_type(4)));
typedef float f32x2 __attribute__((ext_vector_type(2)));

__device__ __forceinline__ float sigmoidf_(float x) {
    return 1.0f / (1.0f + __expf(-x));
}
__device__ __forceinline__ float tanhf_(float x) {
    return 2.0f / (1.0f + __expf(-2.0f * x)) - 1.0f;
}

#define MFMA(a, b, c) __builtin_amdgcn_mfma_f32_32x32x16_bf16(a, b, c, 0, 0, 0)

// ---------------------------------------------------------------------------
// Pack Wh [1024][4096] + Wx [64][4096] (fp32, z-col = g*1024+u) into B-fragment
// order for v_mfma_f32_32x32x16_bf16, split hi/lo bf16. (verified r2-r5)
// Bp[(gcol*68 + kc16)*64 + lane]: gcol = g*32 + bu; col = g*1024+bu*32+(lane&31);
// k = kc16*16 + (lane>>5)*8 + j  (k<1024 -> Wh; else Wx row k-1024)
// ---------------------------------------------------------------------------
__global__ __launch_bounds__(256)
void pack_w(const float* __restrict__ Wh, const float* __restrict__ Wx,
            bf16x8* __restrict__ BpH, bf16x8* __restrict__ BpL)
{
    long id = (long)blockIdx.x * 256 + threadIdx.x;   // 128*68*64 slots
    int lane = (int)(id & 63);
    long rest = id >> 6;
    int kc16 = (int)(rest % NKC16);
    int gcol = (int)(rest / NKC16);                   // 0..127
    int col = (gcol >> 5) * Uq + (gcol & 31) * 32 + (lane & 31);
    int k0 = kc16 * 16 + (lane >> 5) * 8;
    bf16x8 hv, lv;
#pragma unroll
    for (int j = 0; j < 8; ++j) {
        int k = k0 + j;
        float v = (k < Uq) ? Wh[(size_t)k * (4 * Uq) + col]
                           : Wx[(size_t)(k - Uq) * (4 * Uq) + col];
        __bf16 h_ = (__bf16)v;
        hv[j] = h_;
        lv[j] = (__bf16)(v - (float)h_);
    }
    BpH[id] = hv;
    BpL[id] = lv;
}

// ---------------------------------------------------------------------------
// Fused LSTM step, MFMA bf16x3 split, ZERO LDS / ZERO barriers in the K-loop.
// h is stored in MFMA A-fragment layout (hi/lo planes), so each wave loads its
// A fragments straight from global (wave-uniform base + lane*16, coalesced 1KB)
// and B fragments likewise. 17 unrolled chunks of {8 dwordx4 loads + 12 MFMA}.
// Block: 64 rows x 32 units, 512 thr = 8 waves; wave = (gate-pair gp, K-q kq).
// Grid: 256 = 8 bm x 32 bu (bid%8 = bu%8 -> all bm-blocks of a bu share an XCD).
// A-frag elem idx (bf16x8 units): (mt*128 + kcg*2 + pl)*64 + lane
//   mt = row/32 (0..15), kcg = k/16 (0..63 for h), pl = 0 hi / 1 lo.
// ---------------------------------------------------------------------------
__global__ __launch_bounds__(512, 2)
void lstm_step(const bf16x8* __restrict__ aph,   // h frags (read)
               const float* __restrict__ xraw,   // warmup x: inputs + t*64
               const bf16x8* __restrict__ apx,   // decode x frags
               int use_frag_x,
               const bf16x8* __restrict__ BpH,
               const bf16x8* __restrict__ BpL,
               const float* __restrict__ bias,   // [4096]
               bf16x8* __restrict__ apw,         // h frags (write)
               float* __restrict__ c_st)         // [512][1024] fp32 in/out
{
    __shared__ float zsd[4][4][32][36];   // [kq][gate][row][unit+pad] : 72 KB

    const int tid = threadIdx.x;
    const int l   = tid & 63;
    const int w   = tid >> 6;
    const int gp  = w & 1;          // gate pair: gates 2gp, 2gp+1
    const int kq  = w >> 1;         // K-quarter: kc16 = 4i + kq
    const int bm  = (int)blockIdx.x >> 5;
    const int bu  = (int)blockIdx.x & 31;
    const int row0 = bm * 64;

    // per-wave global fragment base pointers
    const bf16x8* bh0 = BpH + ((size_t)((2 * gp + 0) * 32 + bu) * NKC16) * 64 + l;
    const bf16x8* bl0 = BpL + ((size_t)((2 * gp + 0) * 32 + bu) * NKC16) * 64 + l;
    const bf16x8* bh1 = BpH + ((size_t)((2 * gp + 1) * 32 + bu) * NKC16) * 64 + l;
    const bf16x8* bl1 = BpL + ((size_t)((2 * gp + 1) * 32 + bu) * NKC16) * 64 + l;
    const bf16x8* a0  = aph + (size_t)(bm * 2 + 0) * 8192 + l;
    const bf16x8* a1  = aph + (size_t)(bm * 2 + 1) * 8192 + l;

    f32x16 acc[2][2];   // [g2][mt]
#pragma unroll
    for (int i = 0; i < 16; ++i) {
        acc[0][0][i] = 0.0f; acc[0][1][i] = 0.0f;
        acc[1][0][i] = 0.0f; acc[1][1][i] = 0.0f;
    }

#pragma unroll
    for (int i = 0; i < 17; ++i) {
        const int kc = 4 * i + kq;
        bf16x8 ah0, al0, ah1, al1;
        if (i < 16) {
            ah0 = a0[(size_t)kc * 128];
            al0 = a0[(size_t)kc * 128 + 64];
            ah1 = a1[(size_t)kc * 128];
            al1 = a1[(size_t)kc * 128 + 64];
        } else if (use_frag_x) {
            const bf16x8* x0 = apx + (size_t)(bm * 2 + 0) * 512 + kq * 128 + l;
            const bf16x8* x1 = apx + (size_t)(bm * 2 + 1) * 512 + kq * 128 + l;
            ah0 = x0[0]; al0 = x0[64];
            ah1 = x1[0]; al1 = x1[64];
        } else {
            // convert raw fp32 inputs to hi/lo frags in-wave (1 of 17 chunks)
            const int ko = kq * 16 + (l >> 5) * 8;
            const float* p0 = xraw + (size_t)(row0 + (l & 31)) * (Tq * Fq) + ko;
            const float* p1 = xraw + (size_t)(row0 + 32 + (l & 31)) * (Tq * Fq) + ko;
            f32x4 u0 = *(const f32x4*)p0, u1 = *(const f32x4*)(p0 + 4);
            f32x4 v0 = *(const f32x4*)p1, v1 = *(const f32x4*)(p1 + 4);
#pragma unroll
            for (int e = 0; e < 4; ++e) {
                float v = u0[e]; __bf16 h_ = (__bf16)v;
                ah0[e] = h_; al0[e] = (__bf16)(v - (float)h_);
                v = u1[e]; h_ = (__bf16)v;
                ah0[4 + e] = h_; al0[4 + e] = (__bf16)(v - (float)h_);
                v = v0[e]; h_ = (__bf16)v;
                ah1[e] = h_; al1[e] = (__bf16)(v - (float)h_);
                v = v1[e]; h_ = (__bf16)v;
                ah1[4 + e] = h_; al1[4 + e] = (__bf16)(v - (float)h_);
            }
        }
        bf16x8 bhA = bh0[(size_t)kc * 64], blA = bl0[(size_t)kc * 64];
        bf16x8 bhB = bh1[(size_t)kc * 64], blB = bl1[(size_t)kc * 64];
        acc[0][0] = MFMA(ah0, bhA, acc[0][0]);
        acc[0][0] = MFMA(al0, bhA, acc[0][0]);
        acc[0][0] = MFMA(ah0, blA, acc[0][0]);
        acc[0][1] = MFMA(ah1, bhA, acc[0][1]);
        acc[0][1] = MFMA(al1, bhA, acc[0][1]);
        acc[0][1] = MFMA(ah1, blA, acc[0][1]);
        acc[1][0] = MFMA(ah0, bhB, acc[1][0]);
        acc[1][0] = MFMA(al0, bhB, acc[1][0]);
        acc[1][0] = MFMA(ah0, blB, acc[1][0]);
        acc[1][1] = MFMA(ah1, bhB, acc[1][1]);
        acc[1][1] = MFMA(al1, bhB, acc[1][1]);
        acc[1][1] = MFMA(ah1, blB, acc[1][1]);
    }

    // ---- epilogue: K-quarter reduce + gates + state update (2 M-half passes) ----
    // C frag: col(unit) = l&31, row = (r&3) + 8*(r>>2) + 4*(l>>5)
#pragma unroll
    for (int mh = 0; mh < 2; ++mh) {
#pragma unroll
        for (int g2 = 0; g2 < 2; ++g2)
#pragma unroll
            for (int r = 0; r < 16; ++r) {
                const int rowi = (r & 3) + 8 * (r >> 2) + 4 * (l >> 5);
                zsd[kq][gp * 2 + g2][rowi][l & 31] = acc[g2][mh][r];
            }
        __syncthreads();
        {
            const int row = tid >> 4;          // 0..31
            const int uu  = (tid & 15) * 2;    // 0..30
            const int grow = row0 + mh * 32 + row;
            const int gu   = bu * 32 + uu;
            const size_t gidx = (size_t)grow * Uq + gu;
            float z[4][2];
#pragma unroll
            for (int g = 0; g < 4; ++g)
#pragma unroll
                for (int j = 0; j < 2; ++j)
                    z[g][j] = zsd[0][g][row][uu + j] + zsd[1][g][row][uu + j]
                            + zsd[2][g][row][uu + j] + zsd[3][g][row][uu + j];
            f32x2 bi  = *(const f32x2*)(bias + 0 * Uq + gu);
            f32x2 bf2 = *(const f32x2*)(bias + 1 * Uq + gu);
            f32x2 bg2 = *(const f32x2*)(bias + 2 * Uq + gu);
            f32x2 bo2 = *(const f32x2*)(bias + 3 * Uq + gu);
            f32x2 cv = *(const f32x2*)(c_st + gidx);
            float hval[2];
#pragma unroll
            for (int j = 0; j < 2; ++j) {
                float vi = sigmoidf_(z[0][j] + bi[j]);
                float vf = sigmoidf_(z[1][j] + bf2[j]);
                float vg = tanhf_  (z[2][j] + bg2[j]);
                float vo = sigmoidf_(z[3][j] + bo2[j]);
                float cn = vf * cv[j] + vi * vg;
                cv[j] = cn;
                hval[j] = vo * tanhf_(cn);
            }
            *(f32x2*)(c_st + gidx) = cv;
            // h-frag write: mt = grow>>5, kcw = gu>>4, lane = row+32*((uu>>3)&1), e = uu&7
            const int mt   = bm * 2 + mh;
            const int kcw  = bu * 2 + (uu >> 4);
            const int lnw  = row + 32 * ((uu >> 3) & 1);
            const int e    = uu & 7;
            bf16x2 hh, hl;
            __bf16 a0b = (__bf16)hval[0];
            hh[0] = a0b; hl[0] = (__bf16)(hval[0] - (float)a0b);
            __bf16 a1b = (__bf16)hval[1];
            hh[1] = a1b; hl[1] = (__bf16)(hval[1] - (float)a1b);
            char* base = (char*)apw + ((size_t)(mt * 64 + kcw) * 2) * 1024 + lnw * 16 + e * 2;
            *(bf16x2*)(base)        = hh;   // pl0 (hi)
            *(bf16x2*)(base + 1024) = hl;   // pl1 (lo)
        }
        if (mh == 0) __syncthreads();
    }
}

// ---------------------------------------------------------------------------
// Dense readout from h-fragments: p = h @ Wd + bd; writes out[:, step, :] AND
// the next step's x-fragments (hi/lo) so decode feedback stays in frag domain.
// Grid: 256 blocks (2 rows each) x 256 threads (f = t&63, K-quarter kg = t>>6).
// ---------------------------------------------------------------------------
__global__ __launch_bounds__(256)
void readout(const bf16x8* __restrict__ ap, const float* __restrict__ Wd,
             const float* __restrict__ bd, float* __restrict__ out,
             __bf16* __restrict__ Xdec, int step)
{
    __shared__ float red[2][4][64];
    const int t = threadIdx.x;
    const int f = t & 63, kg = t >> 6;
    const int r0 = (int)blockIdx.x * 2;
    const int mt = r0 >> 5;
    const int l0 = r0 & 31;
    const bf16x8* base = ap + (size_t)mt * 8192;
    float s0 = 0.0f, s1 = 0.0f;
#pragma unroll 4
    for (int kc = kg * 16; kc < kg * 16 + 16; ++kc) {
#pragma unroll
        for (int hl = 0; hl < 2; ++hl) {
            bf16x8 h0h = base[(size_t)kc * 128 + hl * 32 + l0];
            bf16x8 h0l = base[(size_t)kc * 128 + 64 + hl * 32 + l0];
            bf16x8 h1h = base[(size_t)kc * 128 + hl * 32 + l0 + 1];
            bf16x8 h1l = base[(size_t)kc * 128 + 64 + hl * 32 + l0 + 1];
            const float* wp = Wd + ((size_t)kc * 16 + hl * 8) * Fq + f;
#pragma unroll
            for (int e = 0; e < 8; ++e) {
                float wv = wp[(size_t)e * Fq];
                s0 = fmaf((float)h0h[e] + (float)h0l[e], wv, s0);
                s1 = fmaf((float)h1h[e] + (float)h1l[e], wv, s1);
            }
        }
    }
    red[0][kg][f] = s0;
    red[1][kg][f] = s1;
    __syncthreads();
    if (t < 128) {
        const int rr = t >> 6, f2 = t & 63;
        const int row2 = r0 + rr;
        float sum = red[rr][0][f2] + red[rr][1][f2] + red[rr][2][f2] + red[rr][3][f2] + bd[f2];
        out[((size_t)row2 * OSTEPS + step) * Fq + f2] = sum;
        // x-frag scatter for next decode step
        __bf16 hi = (__bf16)sum;
        __bf16 lo = (__bf16)(sum - (float)hi);
        const int kc4 = f2 >> 4;
        const int ln2 = (row2 & 31) + 32 * ((f2 >> 3) & 1);
        const int e2  = f2 & 7;
        size_t b0 = ((size_t)(mt * 4 + kc4) * 2) * 512 + (size_t)ln2 * 8 + e2;  // bf16 units
        Xdec[b0]       = hi;
        Xdec[b0 + 512] = lo;
    }
}

__global__ void zero_ws(f32x4* __restrict__ a, int n) {
    int i = blockIdx.x * 256 + threadIdx.x;
    f32x4 z = {0.0f, 0.0f, 0.0f, 0.0f};
    if (i < n) a[i] = z;
}

extern "C" void kernel_launch(void* const* d_in, const int* in_sizes, int n_in,
                              void* d_out, int out_size, void* d_ws, size_t ws_size,
                              hipStream_t stream) {
    const float* inputs = (const float*)d_in[0];  // [512][128][64]
    const float* Wx     = (const float*)d_in[1];  // [64][4096]
    const float* Wh     = (const float*)d_in[2];  // [1024][4096]
    const float* b      = (const float*)d_in[3];  // [4096]
    const float* Wd     = (const float*)d_in[4];  // [1024][64]
    const float* bd     = (const float*)d_in[5];  // [64]
    float* out = (float*)d_out;

    // ws (bytes): c 0 | ap0 2MB | ap1 4MB | Xdec 6MB | BpH | BpL  (~24.3 MB)
    char* ws = (char*)d_ws;
    float*  c_st = (float*)ws;
    bf16x8* ap0  = (bf16x8*)(ws + 2097152);
    bf16x8* ap1  = (bf16x8*)(ws + 4194304);
    __bf16* Xdec = (__bf16*)(ws + 6291456);
    bf16x8* BpH  = (bf16x8*)(ws + 6291456 + 131072);
    bf16x8* BpL  = BpH + (size_t)128 * NKC16 * 64;

    pack_w<<<2176, 256, 0, stream>>>(Wh, Wx, BpH, BpL);
    zero_ws<<<1024, 256, 0, stream>>>((f32x4*)ws, 262144);   // c + ap0 (4 MB)

    bf16x8* apc = ap0;
    bf16x8* apn = ap1;
    for (int t = 0; t < Tq + OSTEPS - 1; ++t) {
        const int use_frag_x = (t >= Tq) ? 1 : 0;
        const float* xr = inputs + (size_t)t * Fq;   // valid for t < 128; unused after
        lstm_step<<<256, 512, 0, stream>>>(apc, xr, (const bf16x8*)Xdec, use_frag_x,
                                           BpH, BpL, b, apn, c_st);
        bf16x8* tmp = apc; apc = apn; apn = tmp;
        if (t >= Tq - 1)
            readout<<<256, 256, 0, stream>>>(apc, Wd, bd, out, Xdec, t - (Tq - 1));
    }
}

// Round 8
// 2997.989 us; speedup vs baseline: 5.6046x; 1.1292x over previous
//
#include <hip/hip_runtime.h>
#include <math.h>

#define Bq 512
#define Tq 128
#define Fq 64
#define Uq 1024
#define OSTEPS 24
#define NKC16 68

typedef __bf16 bf16x8 __attribute__((ext_vector_type(8)));
typedef __bf16 bf16x2 __attribute__((ext_vector_type(2)));
typedef float f32x16 __attribute__((ext_vector_type(16)));
typedef float f32x4 __attribute__((ext_vector_type(4)));
typedef float f32x2 __attribute__((ext_vector_type(2)));

__device__ __forceinline__ float sigmoidf_(float x) {
    return 1.0f / (1.0f + __expf(-x));
}
__device__ __forceinline__ float tanhf_(float x) {
    return 2.0f / (1.0f + __expf(-2.0f * x)) - 1.0f;
}

#define MFMA(a, b, c) __builtin_amdgcn_mfma_f32_32x32x16_bf16(a, b, c, 0, 0, 0)

#define GLL(gp, lp) __builtin_amdgcn_global_load_lds(                         \
    (const __attribute__((address_space(1))) void*)(gp),                      \
    (__attribute__((address_space(3))) void*)(lp), 16, 0, 0)

// counted-vmcnt barrier: LDS ops drained, up to N global loads stay in flight
#define BARV(N) do {                                                          \
    asm volatile("s_waitcnt vmcnt(" #N ") lgkmcnt(0)" ::: "memory");          \
    __builtin_amdgcn_s_barrier();                                             \
} while (0)
#define BARL() do {                                                           \
    asm volatile("s_waitcnt lgkmcnt(0)" ::: "memory");                        \
    __builtin_amdgcn_s_barrier();                                             \
} while (0)

// ---------------------------------------------------------------------------
// Pack Wh [1024][4096] + Wx [64][4096] (fp32, z-col = g*1024+u) into B-fragment
// order for v_mfma_f32_32x32x16_bf16, split hi/lo bf16. (verified r2-r7)
// ---------------------------------------------------------------------------
__global__ __launch_bounds__(256)
void pack_w(const float* __restrict__ Wh, const float* __restrict__ Wx,
            bf16x8* __restrict__ BpH, bf16x8* __restrict__ BpL)
{
    long id = (long)blockIdx.x * 256 + threadIdx.x;   // 128*68*64 slots
    int lane = (int)(id & 63);
    long rest = id >> 6;
    int kc16 = (int)(rest % NKC16);
    int gcol = (int)(rest / NKC16);                   // 0..127
    int col = (gcol >> 5) * Uq + (gcol & 31) * 32 + (lane & 31);
    int k0 = kc16 * 16 + (lane >> 5) * 8;
    bf16x8 hv, lv;
#pragma unroll
    for (int j = 0; j < 8; ++j) {
        int k = k0 + j;
        float v = (k < Uq) ? Wh[(size_t)k * (4 * Uq) + col]
                           : Wx[(size_t)(k - Uq) * (4 * Uq) + col];
        __bf16 h_ = (__bf16)v;
        hv[j] = h_;
        lv[j] = (__bf16)(v - (float)h_);
    }
    BpH[id] = hv;
    BpL[id] = lv;
}

// ---------------------------------------------------------------------------
// Fused LSTM step: A staged via global_load_lds (3-buffer rotation, 2 ahead),
// B in 3-slot register rotation (2 ahead), counted-vmcnt barriers.
// Block: 64 rows x 32 units, 512 thr = 8 waves; wave = (gate-pair gp, K-q kq).
// Grid: 256 = 8 bm x 32 bu.  h stored in MFMA A-fragment layout (r7-verified):
//   frag elem (mt_g, kc, pl, lane) at bf16x8 index (mt_g*128 + kc*2... )
//   actually ((mt_g)*8192 + kc*128 + pl*64 + lane), mt_g = row/32, kc = k/16.
// LDS chunk layout: buf[b 0..3], slot (kc_off, pl, mt) at ((kc_off*2+pl)*2+mt)*1024.
// ---------------------------------------------------------------------------
__global__ __launch_bounds__(512, 1)
void lstm_step(const bf16x8* __restrict__ aph,   // h frags (read)
               const float* __restrict__ xraw,   // warmup x: inputs + t*64
               const bf16x8* __restrict__ xdec8, // decode x frags
               int use_frag_x,
               const bf16x8* __restrict__ BpH,
               const bf16x8* __restrict__ BpL,
               const float* __restrict__ bias,   // [4096]
               bf16x8* __restrict__ apw,         // h frags (write)
               float* __restrict__ c_st)         // [512][1024] fp32 in/out
{
    // bufs 0..2: h chunks (16KB each); buf 3: x chunk; zsd unions all (72KB)
    __shared__ __align__(16) char smem[73728];
    float (*zsd)[4][32][36] = (float (*)[4][32][36])smem;

    const int tid = threadIdx.x;
    const int l   = tid & 63;
    const int w   = tid >> 6;
    const int gp  = w & 1;          // gate pair: gates 2gp, 2gp+1
    const int kq  = w >> 1;         // K-quarter: kc = 4i + kq
    const int skc = w >> 1;         // staging kc_off
    const int spl = w & 1;          // staging plane
    const int bm  = (int)blockIdx.x >> 5;
    const int bu  = (int)blockIdx.x & 31;
    const int row0 = bm * 64;

    // B fragment base pointers (per-lane)
    const bf16x8* bh0 = BpH + ((size_t)((2 * gp + 0) * 32 + bu) * NKC16) * 64 + l;
    const bf16x8* bl0 = BpL + ((size_t)((2 * gp + 0) * 32 + bu) * NKC16) * 64 + l;
    const bf16x8* bh1 = BpH + ((size_t)((2 * gp + 1) * 32 + bu) * NKC16) * 64 + l;
    const bf16x8* bl1 = BpL + ((size_t)((2 * gp + 1) * 32 + bu) * NKC16) * 64 + l;

    // A GLL per-lane source bases (kc = 4c + skc, plane spl, mt 0/1)
    const bf16x8* as0 = aph + (size_t)(bm * 2 + 0) * 8192 + (size_t)skc * 128 + spl * 64 + l;
    const bf16x8* as1 = aph + (size_t)(bm * 2 + 1) * 8192 + (size_t)skc * 128 + spl * 64 + l;
    // wave-uniform LDS dest slot offset
    const int dslot = ((skc * 2 + spl) * 2) * 1024;

#define STAGE_H(c, b) do {                                                     \
    char* d_ = smem + (b) * 16384 + dslot;                                     \
    GLL(as0 + (size_t)(4 * (c)) * 128, d_);                                    \
    GLL(as1 + (size_t)(4 * (c)) * 128, d_ + 1024);                             \
} while (0)

#define LOADB(s, c) do {                                                       \
    Bh[s][0] = bh0[(size_t)(4 * (c) + kq) * 64];                               \
    Bl[s][0] = bl0[(size_t)(4 * (c) + kq) * 64];                               \
    Bh[s][1] = bh1[(size_t)(4 * (c) + kq) * 64];                               \
    Bl[s][1] = bl1[(size_t)(4 * (c) + kq) * 64];                               \
} while (0)

#define COMPUTE(b, s) do {                                                     \
    const char* bb_ = smem + (b) * 16384;                                      \
    bf16x8 ah0_ = *(const bf16x8*)(bb_ + ((kq * 2 + 0) * 2 + 0) * 1024 + l * 16); \
    bf16x8 al0_ = *(const bf16x8*)(bb_ + ((kq * 2 + 1) * 2 + 0) * 1024 + l * 16); \
    bf16x8 ah1_ = *(const bf16x8*)(bb_ + ((kq * 2 + 0) * 2 + 1) * 1024 + l * 16); \
    bf16x8 al1_ = *(const bf16x8*)(bb_ + ((kq * 2 + 1) * 2 + 1) * 1024 + l * 16); \
    __builtin_amdgcn_s_setprio(1);                                             \
    acc[0][0] = MFMA(ah0_, Bh[s][0], acc[0][0]);                               \
    acc[0][0] = MFMA(al0_, Bh[s][0], acc[0][0]);                               \
    acc[0][0] = MFMA(ah0_, Bl[s][0], acc[0][0]);                               \
    acc[0][1] = MFMA(ah1_, Bh[s][0], acc[0][1]);                               \
    acc[0][1] = MFMA(al1_, Bh[s][0], acc[0][1]);                               \
    acc[0][1] = MFMA(ah1_, Bl[s][0], acc[0][1]);                               \
    acc[1][0] = MFMA(ah0_, Bh[s][1], acc[1][0]);                               \
    acc[1][0] = MFMA(al0_, Bh[s][1], acc[1][0]);                               \
    acc[1][0] = MFMA(ah0_, Bl[s][1], acc[1][0]);                               \
    acc[1][1] = MFMA(ah1_, Bh[s][1], acc[1][1]);                               \
    acc[1][1] = MFMA(al1_, Bh[s][1], acc[1][1]);                               \
    acc[1][1] = MFMA(ah1_, Bl[s][1], acc[1][1]);                               \
    __builtin_amdgcn_s_setprio(0);                                             \
} while (0)

    f32x16 acc[2][2];
#pragma unroll
    for (int i = 0; i < 16; ++i) {
        acc[0][0][i] = 0.0f; acc[0][1][i] = 0.0f;
        acc[1][0][i] = 0.0f; acc[1][1][i] = 0.0f;
    }
    bf16x8 Bh[3][2], Bl[3][2];

    // ---- prologue: x chunk into buf3, then h chunks 0,1 + B(0),B(1) ----
    if (use_frag_x) {
        char* d_ = smem + 3 * 16384 + dslot;
        GLL(xdec8 + ((size_t)((bm * 2 + 0) * 4 + skc) * 2 + spl) * 64 + l, d_);
        GLL(xdec8 + ((size_t)((bm * 2 + 1) * 4 + skc) * 2 + spl) * 64 + l, d_ + 1024);
    } else {
        const int srow = tid >> 3;     // 0..63
        const int o    = tid & 7;      // k-octet
        const float* xp = xraw + (size_t)(row0 + srow) * (Tq * Fq) + o * 8;
        f32x4 v0 = *(const f32x4*)xp;
        f32x4 v1 = *(const f32x4*)(xp + 4);
        bf16x8 hv, lv;
#pragma unroll
        for (int e = 0; e < 4; ++e) {
            __bf16 a = (__bf16)v0[e]; hv[e] = a; lv[e] = (__bf16)(v0[e] - (float)a);
            __bf16 b2 = (__bf16)v1[e]; hv[4 + e] = b2; lv[4 + e] = (__bf16)(v1[e] - (float)b2);
        }
        const int mtx = srow >> 5;
        const int lnx = (srow & 31) + 32 * (o & 1);
        char* xb = smem + 3 * 16384 + (((o >> 1) * 2 + 0) * 2 + mtx) * 1024 + lnx * 16;
        *(bf16x8*)xb          = hv;
        *(bf16x8*)(xb + 2048) = lv;   // plane 1 slot is +2*1024
    }
    STAGE_H(0, 0);
    STAGE_H(1, 1);
    LOADB(0, 0);
    LOADB(1, 1);
    BARV(10);   // GLL(0) complete (10 newer ops in flight)

    // ---- pipelined K loop: 17 chunks (0..15 = h, 16 = x) ----
#pragma unroll
    for (int i = 0; i < 17; ++i) {
        if (i <= 13) STAGE_H(i + 2, (i + 2) % 3);
        if (i <= 14) LOADB((i + 2) % 3, i + 2);
        COMPUTE(i == 16 ? 3 : i % 3, i % 3);
        if (i <= 13)      BARV(10);
        else if (i == 14) BARV(8);
        else if (i == 15) BARV(4);
    }
    BARL();   // all fragment reads retired; smem becomes zsd

    // ---- epilogue: K-quarter reduce + gates + state update (2 M-half passes) ----
    // C frag: col(unit) = l&31, row = (r&3) + 8*(r>>2) + 4*(l>>5)
#pragma unroll
    for (int mh = 0; mh < 2; ++mh) {
#pragma unroll
        for (int g2 = 0; g2 < 2; ++g2)
#pragma unroll
            for (int r = 0; r < 16; ++r) {
                const int rowi = (r & 3) + 8 * (r >> 2) + 4 * (l >> 5);
                zsd[kq][gp * 2 + g2][rowi][l & 31] = acc[g2][mh][r];
            }
        __syncthreads();
        {
            const int row = tid >> 4;          // 0..31
            const int uu  = (tid & 15) * 2;    // 0..30
            const int grow = row0 + mh * 32 + row;
            const int gu   = bu * 32 + uu;
            const size_t gidx = (size_t)grow * Uq + gu;
            float z[4][2];
#pragma unroll
            for (int g = 0; g < 4; ++g)
#pragma unroll
                for (int j = 0; j < 2; ++j)
                    z[g][j] = zsd[0][g][row][uu + j] + zsd[1][g][row][uu + j]
                            + zsd[2][g][row][uu + j] + zsd[3][g][row][uu + j];
            f32x2 bi  = *(const f32x2*)(bias + 0 * Uq + gu);
            f32x2 bf2 = *(const f32x2*)(bias + 1 * Uq + gu);
            f32x2 bg2 = *(const f32x2*)(bias + 2 * Uq + gu);
            f32x2 bo2 = *(const f32x2*)(bias + 3 * Uq + gu);
            f32x2 cv = *(const f32x2*)(c_st + gidx);
            float hval[2];
#pragma unroll
            for (int j = 0; j < 2; ++j) {
                float vi = sigmoidf_(z[0][j] + bi[j]);
                float vf = sigmoidf_(z[1][j] + bf2[j]);
                float vg = tanhf_  (z[2][j] + bg2[j]);
                float vo = sigmoidf_(z[3][j] + bo2[j]);
                float cn = vf * cv[j] + vi * vg;
                cv[j] = cn;
                hval[j] = vo * tanhf_(cn);
            }
            *(f32x2*)(c_st + gidx) = cv;
            // h-frag write (r7-verified): mt = grow>>5, kcw = gu>>4,
            // lane = row + 32*((uu>>3)&1), elem = uu&7
            const int mt   = bm * 2 + mh;
            const int kcw  = bu * 2 + (uu >> 4);
            const int lnw  = row + 32 * ((uu >> 3) & 1);
            const int e    = uu & 7;
            bf16x2 hh, hl;
            __bf16 a0b = (__bf16)hval[0];
            hh[0] = a0b; hl[0] = (__bf16)(hval[0] - (float)a0b);
            __bf16 a1b = (__bf16)hval[1];
            hh[1] = a1b; hl[1] = (__bf16)(hval[1] - (float)a1b);
            char* base = (char*)apw + ((size_t)(mt * 64 + kcw) * 2) * 1024 + lnw * 16 + e * 2;
            *(bf16x2*)(base)        = hh;   // pl0 (hi)
            *(bf16x2*)(base + 1024) = hl;   // pl1 (lo)
        }
        if (mh == 0) __syncthreads();
    }
#undef STAGE_H
#undef LOADB
#undef COMPUTE
}

// ---------------------------------------------------------------------------
// Dense readout from h-fragments: p = h @ Wd + bd; writes out[:, step, :] AND
// the next step's x-fragments (hi/lo). (r7-verified)
// ---------------------------------------------------------------------------
__global__ __launch_bounds__(256)
void readout(const bf16x8* __restrict__ ap, const float* __restrict__ Wd,
             const float* __restrict__ bd, float* __restrict__ out,
             __bf16* __restrict__ Xdec, int step)
{
    __shared__ float red[2][4][64];
    const int t = threadIdx.x;
    const int f = t & 63, kg = t >> 6;
    const int r0 = (int)blockIdx.x * 2;
    const int mt = r0 >> 5;
    const int l0 = r0 & 31;
    const bf16x8* base = ap + (size_t)mt * 8192;
    float s0 = 0.0f, s1 = 0.0f;
#pragma unroll 4
    for (int kc = kg * 16; kc < kg * 16 + 16; ++kc) {
#pragma unroll
        for (int hl = 0; hl < 2; ++hl) {
            bf16x8 h0h = base[(size_t)kc * 128 + hl * 32 + l0];
            bf16x8 h0l = base[(size_t)kc * 128 + 64 + hl * 32 + l0];
            bf16x8 h1h = base[(size_t)kc * 128 + hl * 32 + l0 + 1];
            bf16x8 h1l = base[(size_t)kc * 128 + 64 + hl * 32 + l0 + 1];
            const float* wp = Wd + ((size_t)kc * 16 + hl * 8) * Fq + f;
#pragma unroll
            for (int e = 0; e < 8; ++e) {
                float wv = wp[(size_t)e * Fq];
                s0 = fmaf((float)h0h[e] + (float)h0l[e], wv, s0);
                s1 = fmaf((float)h1h[e] + (float)h1l[e], wv, s1);
            }
        }
    }
    red[0][kg][f] = s0;
    red[1][kg][f] = s1;
    __syncthreads();
    if (t < 128) {
        const int rr = t >> 6, f2 = t & 63;
        const int row2 = r0 + rr;
        float sum = red[rr][0][f2] + red[rr][1][f2] + red[rr][2][f2] + red[rr][3][f2] + bd[f2];
        out[((size_t)row2 * OSTEPS + step) * Fq + f2] = sum;
        __bf16 hi = (__bf16)sum;
        __bf16 lo = (__bf16)(sum - (float)hi);
        const int kc4 = f2 >> 4;
        const int ln2 = (row2 & 31) + 32 * ((f2 >> 3) & 1);
        const int e2  = f2 & 7;
        size_t b0 = ((size_t)(mt * 4 + kc4) * 2) * 512 + (size_t)ln2 * 8 + e2;  // bf16 units
        Xdec[b0]       = hi;
        Xdec[b0 + 512] = lo;
    }
}

__global__ void zero_ws(f32x4* __restrict__ a, int n) {
    int i = blockIdx.x * 256 + threadIdx.x;
    f32x4 z = {0.0f, 0.0f, 0.0f, 0.0f};
    if (i < n) a[i] = z;
}

extern "C" void kernel_launch(void* const* d_in, const int* in_sizes, int n_in,
                              void* d_out, int out_size, void* d_ws, size_t ws_size,
                              hipStream_t stream) {
    const float* inputs = (const float*)d_in[0];  // [512][128][64]
    const float* Wx     = (const float*)d_in[1];  // [64][4096]
    const float* Wh     = (const float*)d_in[2];  // [1024][4096]
    const float* b      = (const float*)d_in[3];  // [4096]
    const float* Wd     = (const float*)d_in[4];  // [1024][64]
    const float* bd     = (const float*)d_in[5];  // [64]
    float* out = (float*)d_out;

    // ws (bytes): c 0 | ap0 2MB | ap1 4MB | Xdec 6MB | BpH | BpL  (~24.3 MB)
    char* ws = (char*)d_ws;
    float*  c_st = (float*)ws;
    bf16x8* ap0  = (bf16x8*)(ws + 2097152);
    bf16x8* ap1  = (bf16x8*)(ws + 4194304);
    __bf16* Xdec = (__bf16*)(ws + 6291456);
    bf16x8* BpH  = (bf16x8*)(ws + 6291456 + 131072);
    bf16x8* BpL  = BpH + (size_t)128 * NKC16 * 64;

    pack_w<<<2176, 256, 0, stream>>>(Wh, Wx, BpH, BpL);
    zero_ws<<<1024, 256, 0, stream>>>((f32x4*)ws, 262144);   // c + ap0 (4 MB)

    bf16x8* apc = ap0;
    bf16x8* apn = ap1;
    for (int t = 0; t < Tq + OSTEPS - 1; ++t) {
        const int use_frag_x = (t >= Tq) ? 1 : 0;
        const float* xr = inputs + (size_t)t * Fq;   // valid for t < 128; unused after
        lstm_step<<<256, 512, 0, stream>>>(apc, xr, (const bf16x8*)Xdec, use_frag_x,
                                           BpH, BpL, b, apn, c_st);
        bf16x8* tmp = apc; apc = apn; apn = tmp;
        if (t >= Tq - 1)
            readout<<<256, 256, 0, stream>>>(apc, Wd, bd, out, Xdec, t - (Tq - 1));
    }
}